// Round 1
// 1095.287 us; speedup vs baseline: 1.0232x; 1.0232x over previous
//
#include <hip/hip_runtime.h>
#include <hip/hip_fp16.h>

#define L_    2048
#define D_    64
#define QT    64
#define NKT   32            // 2048 / 64
#define KP16  72            // halves per K row in LDS (64 data + 8 pad)
#define VTP   72            // u16 pitch for Vt rows (d-major)
#define PBP   72            // u16 pitch for Pbuf rows

typedef _Float16 half8  __attribute__((ext_vector_type(8)));
typedef _Float16 half4  __attribute__((ext_vector_type(4)));
typedef _Float16 half2v __attribute__((ext_vector_type(2)));
typedef float    f32x4  __attribute__((ext_vector_type(4)));

__device__ __forceinline__ f32x4 mfma16f(half8 a, half8 b, f32x4 c) {
    return __builtin_amdgcn_mfma_f32_16x16x32_f16(a, b, c, 0, 0, 0);
}

// raw barrier: no vmcnt drain (prefetch loads + att_w stores stay in flight).
// lgkmcnt(0) with memory clobber orders LDS traffic around the barrier.
#define FENCE_BAR() do { asm volatile("s_waitcnt lgkmcnt(0)" ::: "memory"); \
                         __builtin_amdgcn_s_barrier();                       \
                         asm volatile("" ::: "memory"); } while (0)

__global__ __launch_bounds__(256, 4)
void attn_fused(const float* __restrict__ Qg, const float* __restrict__ Kg,
                const float* __restrict__ Vg, const int* __restrict__ validg,
                const float* __restrict__ scaleg,
                float* __restrict__ outR, float* __restrict__ outW)
{
    // K tile now fp16 in LDS (converted once at stage time).
    // row-major [64][72]: frag read = single b128 at row*144 + qd*16 (+64B),
    // 144B row stride -> 8 lanes per 4-bank window = b128 floor, conflict-free.
    __shared__ __attribute__((aligned(16))) _Float16 Klds[64 * KP16];   // 9216 B
    __shared__ __attribute__((aligned(16))) _Float16 Vt[64 * VTP];      // 9216 B
    __shared__ __attribute__((aligned(16))) _Float16 Pbuf[64 * PBP];    // 9216 B

    const int tid  = threadIdx.x;
    const int wv   = tid >> 6;
    const int lane = tid & 63;
    const int ln   = lane & 15;
    const int qd   = lane >> 4;

    // XCD-grouping swizzle: 4 bh per XCD -> K/V L2-resident per XCD
    const int bidx = blockIdx.x;
    const int bh   = (bidx & 7) * 4 + ((bidx >> 3) & 3);
    const int qt   = bidx >> 5;

    const float scale = scaleg[0];

    const float* Qb = Qg + ((size_t)bh * L_ + (size_t)qt * QT) * D_;
    const float* Kb = Kg + (size_t)bh * L_ * D_;
    const float* Vb = Vg + (size_t)bh * L_ * D_;
    const int*   Mb = validg + ((size_t)bh * L_ + (size_t)qt * QT) * (size_t)L_;
    float* Ob = outR + ((size_t)bh * L_ + (size_t)qt * QT) * D_;
    float* Wb = outW + ((size_t)bh * L_ + (size_t)qt * QT) * (size_t)L_;

    // ---- persistent Q A-fragments (fp16): A[m=ln][k=qd*8+j], frag f: d = f*32.. ----
    half8 aF[2];
    {
        const float* qrow = Qb + (size_t)(wv * 16 + ln) * D_;
#pragma unroll
        for (int f = 0; f < 2; ++f) {
            f32x4 x0 = *(const f32x4*)(qrow + f * 32 + qd * 8);
            f32x4 x1 = *(const f32x4*)(qrow + f * 32 + qd * 8 + 4);
            half8 h;
#pragma unroll
            for (int j = 0; j < 4; ++j) { h[j] = (_Float16)x0[j]; h[4 + j] = (_Float16)x1[j]; }
            aF[f] = h;
        }
    }

    // ---- reg-staged K: thread loads 4 f32x4 (fully coalesced 1KB/wave/instr),
    //      writes 4 half4 (b64, 4 lanes/2-bank window = floor) ----
    f32x4 kreg[4];
    const int kt4 = tid >> 4;           // [0,16)
    const int kc4 = (tid & 15) * 4;     // col chunk
    auto loadK = [&](int kt) {
        const float* base = Kb + (size_t)kt * (64 * 64);
#pragma unroll
        for (int j = 0; j < 4; ++j)
            kreg[j] = *(const f32x4*)(base + (size_t)(j * 256 + tid) * 4);
    };
    auto writeK = [&]() {
#pragma unroll
        for (int j = 0; j < 4; ++j) {
            const int row = j * 16 + kt4;
            half4 h;
#pragma unroll
            for (int e = 0; e < 4; ++e) h[e] = (_Float16)kreg[j][e];
            *(half4*)&Klds[row * KP16 + kc4] = h;
        }
    };

    // ---- reg-staged V (same transpose+swizzle layout as before) ----
    f32x4 vreg[4];
    const int rp = tid >> 3;            // kk-pair 2rp,2rp+1
    const int vc = tid & 7;             // d-chunk
    const int dc = vc * 8;
    auto loadV = [&](int kt) {
        const float* v0p = Vb + ((size_t)kt * 64 + 2 * rp) * 64 + dc;
        vreg[0] = *(const f32x4*)v0p;
        vreg[1] = *(const f32x4*)(v0p + 4);
        vreg[2] = *(const f32x4*)(v0p + 64);
        vreg[3] = *(const f32x4*)(v0p + 68);
    };
    auto writeV = [&]() {
        const int g = (rp >> 2) ^ vc;   // (d>>3)&7 == vc for d in [dc,dc+8)
#pragma unroll
        for (int i = 0; i < 8; ++i) {
            float f0 = (i < 4) ? vreg[0][i] : vreg[1][i - 4];
            float f1 = (i < 4) ? vreg[2][i] : vreg[3][i - 4];
            half2v h; h[0] = (_Float16)f0; h[1] = (_Float16)f1;
            const int d = dc + i;
            *(half2v*)&Vt[d * VTP + 8 * g + 2 * (rp & 3)] = h;
        }
    };

    // ---- mask prefetch regs ----
    int mv[16];
    const int* maskbase = Mb + (size_t)(wv * 16 + qd * 4) * L_ + ln;
    auto loadM = [&](int kt) {
#pragma unroll
        for (int ct = 0; ct < 4; ++ct)
#pragma unroll
            for (int r = 0; r < 4; ++r)
                mv[ct * 4 + r] = maskbase[(size_t)r * L_ + kt * 64 + ct * 16];
    };

    auto kfrags = [&](int kr, half8& b0, half8& b1) {
        const _Float16* kp = &Klds[kr * KP16 + qd * 8];
        b0 = *(const half8*)kp;
        b1 = *(const half8*)(kp + 32);
    };

    // per-kt mask bits parked in the block's OWN result slab (16 KiB, exact fit;
    // epilogue overwrites it after all bits are consumed). Each thread reads back
    // only the address it wrote -> no cross-thread hazard.
    unsigned short* bitsSlab = (unsigned short*)Ob;

    // ================= PHASE 1: row sums =================
    float lsum[4] = {0.f, 0.f, 0.f, 0.f};
    loadK(0); loadM(0);
    for (int kt = 0; kt < NKT; ++kt) {
        FENCE_BAR();                         // previous tile's readers done
        writeK();                            // waits (counted) on kreg loads from last iter
        unsigned bits = 0;
#pragma unroll
        for (int i = 0; i < 16; ++i) bits |= (mv[i] > 0 ? 1u : 0u) << i;
        if (kt + 1 < NKT) { loadK(kt + 1); loadM(kt + 1); }   // in flight across barriers
        FENCE_BAR();                         // K(kt) visible
        bitsSlab[kt * 256 + tid] = (unsigned short)bits;      // fire-and-forget
#pragma unroll
        for (int ct = 0; ct < 4; ++ct) {
            half8 b0, b1;
            kfrags(ct * 16 + ln, b0, b1);
            f32x4 acc = {0.f, 0.f, 0.f, 0.f};
            acc = mfma16f(aF[0], b0, acc);
            acc = mfma16f(aF[1], b1, acc);
#pragma unroll
            for (int r = 0; r < 4; ++r) {
                float bit = (float)((bits >> (ct * 4 + r)) & 1u);
                lsum[r] += bit * __expf(acc[r] * scale);
            }
        }
    }

    float invl[4];
#pragma unroll
    for (int r = 0; r < 4; ++r) {
        float v = lsum[r];
        v += __shfl_xor(v, 1);
        v += __shfl_xor(v, 2);
        v += __shfl_xor(v, 4);
        v += __shfl_xor(v, 8);
        invl[r] = v > 0.f ? 1.f / v : 0.f;   // fully-masked row -> zeros
    }

    // bits stores must complete before we read them back (one-time drain)
    asm volatile("s_waitcnt vmcnt(0)" ::: "memory");

    // ================= PHASE 2: recompute S, write att_w, accumulate O =================
    f32x4 accO[4];
#pragma unroll
    for (int i = 0; i < 4; ++i) accO[i] = (f32x4){0.f, 0.f, 0.f, 0.f};

    loadK(0); loadV(0);
    unsigned bcur = bitsSlab[tid];
    for (int kt = 0; kt < NKT; ++kt) {
        FENCE_BAR();                         // readers of previous K/V tile done
        writeK();
        writeV();
        unsigned bnext = 0;
        if (kt + 1 < NKT) {
            loadK(kt + 1); loadV(kt + 1);
            bnext = bitsSlab[(kt + 1) * 256 + tid];
        }
        FENCE_BAR();                         // tile kt visible
        const unsigned bits = bcur;
        // QK^T + softmax -> Pbuf (own-wave rows, no barrier needed before PV)
#pragma unroll
        for (int ct = 0; ct < 4; ++ct) {
            half8 b0, b1;
            kfrags(ct * 16 + ln, b0, b1);
            f32x4 acc = {0.f, 0.f, 0.f, 0.f};
            acc = mfma16f(aF[0], b0, acc);
            acc = mfma16f(aF[1], b1, acc);
#pragma unroll
            for (int r = 0; r < 4; ++r) {
                const int qrow = wv * 16 + qd * 4 + r;
                float bit = (float)((bits >> (ct * 4 + r)) & 1u);
                float p = bit * __expf(acc[r] * scale) * invl[r];
                Pbuf[qrow * PBP + ct * 16 + ln] = (_Float16)p;
            }
        }
        // A-frags of P (row = wv*16+ln, contiguous kk)
        half8 p0 = *(const half8*)&Pbuf[(wv * 16 + ln) * PBP + qd * 8];
        half8 p1 = *(const half8*)&Pbuf[(wv * 16 + ln) * PBP + 32 + qd * 8];
        {   // vectorized att_w store from the round-tripped fragments
            float* wp = Wb + (size_t)(wv * 16 + ln) * L_ + kt * 64;
            f32x4 s0, s1, s2, s3;
#pragma unroll
            for (int j = 0; j < 4; ++j) {
                s0[j] = (float)p0[j];     s1[j] = (float)p0[4 + j];
                s2[j] = (float)p1[j];     s3[j] = (float)p1[4 + j];
            }
            *(f32x4*)(wp + qd * 8)          = s0;
            *(f32x4*)(wp + qd * 8 + 4)      = s1;
            *(f32x4*)(wp + 32 + qd * 8)     = s2;
            *(f32x4*)(wp + 32 + qd * 8 + 4) = s3;
        }
        // PV: O += P * V  (B-frags are single b128 thanks to the swizzle)
#pragma unroll
        for (int c2 = 0; c2 < 4; ++c2) {
            const int d  = c2 * 16 + ln;
            const int g2 = (d >> 3) & 7;
            half8 v0 = *(const half8*)&Vt[d * VTP + 8 * (qd ^ g2)];
            half8 v1 = *(const half8*)&Vt[d * VTP + 8 * ((4 + qd) ^ g2)];
            accO[c2] = mfma16f(p0, v0, accO[c2]);
            accO[c2] = mfma16f(p1, v1, accO[c2]);
        }
        bcur = bnext;
    }

    // ---- write result (overwrites bitsSlab region; all bits already consumed) ----
#pragma unroll
    for (int c2 = 0; c2 < 4; ++c2)
#pragma unroll
        for (int r = 0; r < 4; ++r)
            Ob[(size_t)(wv * 16 + qd * 4 + r) * D_ + (c2 * 16 + ln)] = accO[c2][r];
}

extern "C" void kernel_launch(void* const* d_in, const int* in_sizes, int n_in,
                              void* d_out, int out_size, void* d_ws, size_t ws_size,
                              hipStream_t stream) {
    const float* q     = (const float*)d_in[0];
    const float* k     = (const float*)d_in[1];
    const float* v     = (const float*)d_in[2];
    const int*   valid = (const int*)d_in[3];
    const float* scale = (const float*)d_in[4];

    float* out_res  = (float*)d_out;
    float* out_attw = out_res + (size_t)2 * 16 * L_ * D_;

    dim3 grid(2 * 16 * (L_ / QT));   // 1024
    dim3 block(256);
    attn_fused<<<grid, block, 0, stream>>>(q, k, v, valid, scale, out_res, out_attw);
}